// Round 12
// baseline (346.948 us; speedup 1.0000x reference)
//
#include <hip/hip_runtime.h>

#define Nn 100000
#define Ne 100000
#define NNZC 1600000
#define NBLK 256          // blocks for scatter
#define CHUNK 6250        // NNZC / NBLK
#define BSH 8             // bucket = idx >> 8 (256 ids per bucket)
#define NBK 391           // ceil(100000/256)
#define CAPB 5120         // padded bucket capacity (mean 4096 + 16 sigma)
#define GEMM_TOTAL 391    // 256-row gemm tiles
#define LCAP 2816         // per-half-bucket LDS perm capacity (mean 2048 + 17 sigma)
#define NHB 782           // 2 half-buckets per bucket

typedef __attribute__((ext_vector_type(8))) short short8;
typedef __attribute__((ext_vector_type(4))) float floatx4;

__device__ inline unsigned short f2bf(float f) {
    union { float f; unsigned int i; } c; c.f = f;
    unsigned int i = c.i;
    return (unsigned short)((i + 0x7fffu + ((i >> 16) & 1u)) >> 16);  // RNE
}
__device__ inline unsigned int f2bf2(float lo, float hi) {  // packed RNE
    union { float f; unsigned int i; } a, b;
    a.f = lo; b.f = hi;
    const unsigned int x = (a.i + 0x7fffu + ((a.i >> 16) & 1u)) >> 16;
    const unsigned int y = (b.i + 0x7fffu + ((b.i >> 16) & 1u)) & 0xffff0000u;
    return x | y;
}

// LDS for the scatter+gemm kernel
union FusedLds {
    unsigned short wlds[128 * 136];            // 34816 B (gemm W staging)
    struct { int a[NBK]; int b[NBK]; } s;      // 3128 B (scatter counts/cursors)
};

// ---- gemm block body: h[256 rows] = bf16(x @ W); W staged ONCE, 4 row-groups ----
__device__ inline void gemm_block256(int gb, const float* __restrict__ x,
                                     const float* __restrict__ w,
                                     unsigned short* __restrict__ h,
                                     unsigned short* wlds, int tid) {
    const int wave = tid >> 6, lane = tid & 63;
    const int q = lane >> 4, r16 = lane & 15;

    // stage W: w[k*128+n] fp32 -> wlds[n*136+k] bf16
    for (int i = tid; i < 4096; i += 256) {
        const int k = i >> 5;
        const int n0 = (i & 31) << 2;
        const float4 wv = *(const float4*)(w + k * 128 + n0);
        wlds[(n0 + 0) * 136 + k] = f2bf(wv.x);
        wlds[(n0 + 1) * 136 + k] = f2bf(wv.y);
        wlds[(n0 + 2) * 136 + k] = f2bf(wv.z);
        wlds[(n0 + 3) * 136 + k] = f2bf(wv.w);
    }
    __syncthreads();

#pragma unroll 1
    for (int rg = 0; rg < 4; ++rg) {
        const int row0 = gb * 256 + rg * 64 + wave * 16;
        const int rrow = min(row0 + r16, Nn - 1);

        floatx4 acc[8];
#pragma unroll
        for (int jb = 0; jb < 8; ++jb) acc[jb] = (floatx4){0.f, 0.f, 0.f, 0.f};

        const float* ap = x + (size_t)rrow * 128 + q * 8;
#pragma unroll
        for (int kk = 0; kk < 4; ++kk) {
            const float4 a0 = *(const float4*)(ap + kk * 32);
            const float4 a1 = *(const float4*)(ap + kk * 32 + 4);
            union { unsigned int u[4]; short8 s; } xf;
            xf.u[0] = f2bf2(a0.x, a0.y);
            xf.u[1] = f2bf2(a0.z, a0.w);
            xf.u[2] = f2bf2(a1.x, a1.y);
            xf.u[3] = f2bf2(a1.z, a1.w);
            const unsigned short* wp = wlds + kk * 32 + q * 8;
#pragma unroll
            for (int jb = 0; jb < 8; ++jb) {
                const short8 wf = *(const short8*)(wp + (jb * 16 + r16) * 136);
                acc[jb] = __builtin_amdgcn_mfma_f32_16x16x32_bf16(wf, xf.s, acc[jb], 0, 0, 0);
            }
        }

        if (row0 + r16 < Nn) {
            unsigned short* hb = h + (size_t)(row0 + r16) * 128 + q * 4;
#pragma unroll
            for (int jb = 0; jb < 8; ++jb) {
                uint2 o;
                o.x = f2bf2(acc[jb][0], acc[jb][1]);
                o.y = f2bf2(acc[jb][2], acc[jb][3]);
                *(uint2*)(hb + jb * 16) = o;
            }
        }
    }
}

// ---- fused: padded-bucket scatter (blocks [0,NBLK)) + gemm256 (rest) ----
__global__ __launch_bounds__(256) void scatter_gemm_kernel(
        const int* __restrict__ nidx, const int* __restrict__ eidx,
        int* __restrict__ gcurN, int* __restrict__ gcurE,
        unsigned int* __restrict__ pairsN, unsigned int* __restrict__ pairsE,
        const float* __restrict__ x, const float* __restrict__ w,
        unsigned short* __restrict__ h) {
    __shared__ FusedLds sm;
    const int tid = threadIdx.x;
    if (blockIdx.x < NBLK) {
        // pass 1: count
        for (int j = tid; j < NBK; j += 256) { sm.s.a[j] = 0; sm.s.b[j] = 0; }
        __syncthreads();
        const int base = blockIdx.x * CHUNK;
        for (int i = base + tid; i < base + CHUNK; i += 256) {
            atomicAdd(&sm.s.a[nidx[i] >> BSH], 1);
            atomicAdd(&sm.s.b[eidx[i] >> BSH], 1);
        }
        __syncthreads();
        // reserve contiguous ranges via memory-side returning atomics
        for (int j = tid; j < NBK; j += 256) {
            sm.s.a[j] = atomicAdd(&gcurN[j], sm.s.a[j]);
            sm.s.b[j] = atomicAdd(&gcurE[j], sm.s.b[j]);
        }
        __syncthreads();
        // pass 2: place (idx re-read is L2-hot)
        for (int i = base + tid; i < base + CHUNK; i += 256) {
            const int n = nidx[i], e = eidx[i];
            const int pn = atomicAdd(&sm.s.a[n >> BSH], 1);
            if (pn < CAPB)
                pairsN[(size_t)(n >> BSH) * CAPB + pn] =
                    ((unsigned int)e << 8) | (unsigned int)(n & 255);
            const int pe = atomicAdd(&sm.s.b[e >> BSH], 1);
            if (pe < CAPB)
                pairsE[(size_t)(e >> BSH) * CAPB + pe] =
                    ((unsigned int)n << 8) | (unsigned int)(e & 255);
        }
    } else {
        gemm_block256(blockIdx.x - NBLK, x, w, h, sm.wlds, tid);
    }
}

// ---- bucket-gather: block owns 128 ids (half bucket); sort in LDS, then the
// proven 8-deep streaming gather fed from LDS CSR (no perm/offs global traffic).
// MODE 0: nodes->edges (h -> ef, bf16 out); MODE 1: edges->nodes (ef -> out + bias).
template <int MODE>
__global__ __launch_bounds__(256) void bucketgather_kernel(
        const unsigned int* __restrict__ pairs, const int* __restrict__ gcur,
        const void* __restrict__ srcv, const float* __restrict__ bias,
        void* __restrict__ outv) {
    __shared__ int perm_lds[LCAP];      // 11264 B
    __shared__ int offs_lds[129];
    __shared__ int cnt[128];
    __shared__ int cur[128];
    __shared__ int tmp[2][128];
    const int b = blockIdx.x >> 1;
    const int half = blockIdx.x & 1;
    const int tid = threadIdx.x;
    const int wave = tid >> 6, lane = tid & 63;

    const int fill = min(gcur[b], CAPB);
    const unsigned int* pb = pairs + (size_t)b * CAPB;

    // count this half's local ids (bit 7 selects half; low 7 bits = local id)
    if (tid < 128) cnt[tid] = 0;
    __syncthreads();
    for (int i = tid; i < fill; i += 256) {
        const unsigned int p = pb[i];
        if ((int)((p >> 7) & 1u) == half) atomicAdd(&cnt[p & 127u], 1);
    }
    __syncthreads();
    // exclusive scan of 128 counts (Hillis-Steele on tid<128)
    int v = 0, pin = 0;
    if (tid < 128) { v = cnt[tid]; tmp[0][tid] = v; }
    for (int off = 1; off < 128; off <<= 1) {
        __syncthreads();
        if (tid < 128) {
            int val = tmp[pin][tid];
            if (tid >= off) val += tmp[pin][tid - off];
            tmp[1 - pin][tid] = val;
        }
        pin ^= 1;
    }
    __syncthreads();
    if (tid < 128) {
        const int excl = tmp[pin][tid] - v;
        offs_lds[tid] = excl;
        cur[tid] = excl;
        if (tid == 127) offs_lds[128] = tmp[pin][127];
    }
    __syncthreads();
    // place (bucket re-read is L2-hot; sibling half-block shares the lines)
    for (int i = tid; i < fill; i += 256) {
        const unsigned int p = pb[i];
        if ((int)((p >> 7) & 1u) == half) {
            const int pos = atomicAdd(&cur[p & 127u], 1);
            if (pos < LCAP) perm_lds[pos] = (int)(p >> 8);
        }
    }
    __syncthreads();

    // ---- proven flattened streaming gather, LDS-fed (wave owns 32 ids) ----
    const int i0 = wave << 5;
    const int start = offs_lds[i0];
    const int end = offs_lds[i0 + 32];
    const int pmax = min(offs_lds[128], LCAP) - 1;
    const unsigned int l4 = (unsigned int)lane << 2;
    const char* src = (const char*)srcv;

    float bx = 0.f, by = 0.f;
    if (MODE == 1) {
        const float2 bb = ((const float2*)bias)[lane];
        bx = bb.x; by = bb.y;
    }

    float ax = 0.f, ay = 0.f;
    int e = i0;
    int seg_start = start;
    int nb = offs_lds[i0 + 1];
    const int gidbase = (b << 8) + (half << 7);

    auto flush = [&](int deg) {
        const int gid = gidbase + e;
        if (gid < 100000) {
            const float sinv = deg ? 1.f / (float)deg : 0.f;
            if (MODE == 0) {
                *(unsigned int*)((char*)outv + (((size_t)gid) << 8) + l4) =
                    f2bf2(ax * sinv, ay * sinv);
            } else {
                float2 o;
                o.x = ax * sinv + bx;
                o.y = ay * sinv + by;
                *(float2*)((char*)outv + (((size_t)gid) << 9) + ((size_t)l4 << 1)) = o;
            }
        }
        ax = 0.f; ay = 0.f;
        ++e;
    };

    int myv = 0;
    for (int i = start; i < end; i += 8) {
        const int t = (i - start) & 63;
        if (t == 0) myv = perm_lds[min(i + lane, pmax)];   // ds_read window
        const int m = min(end - i, 8);
        unsigned int a[8], u[8];
#pragma unroll
        for (int j = 0; j < 8; ++j)
            a[j] = ((unsigned int)__shfl(myv, t + (j < m ? j : m - 1), 64) << 8) | l4;
#pragma unroll
        for (int j = 0; j < 8; ++j) u[j] = *(const unsigned int*)(src + a[j]);
#pragma unroll
        for (int j = 0; j < 8; ++j) {
            if (j < m) {  // wave-uniform
                while (i + j == nb) {  // segment boundary (handles empty segments)
                    flush(nb - seg_start);
                    seg_start = nb;
                    nb = offs_lds[e + 1];
                }
                ax += __uint_as_float(u[j] << 16);
                ay += __uint_as_float(u[j] & 0xffff0000u);
            }
        }
    }
    while (e < i0 + 32) {    // trailing (possibly empty) segments
        flush(end - seg_start);
        seg_start = end;
    }
}

extern "C" void kernel_launch(void* const* d_in, const int* in_sizes, int n_in,
                              void* d_out, int out_size, void* d_ws, size_t ws_size,
                              hipStream_t stream) {
    const float* x = (const float*)d_in[0];
    const float* w = (const float*)d_in[1];
    const float* bias = (const float*)d_in[2];
    const int* hei = (const int*)d_in[3];
    const int* nidx = hei;            // row 0: node indices
    const int* eidx = hei + NNZC;     // row 1: edge indices
    float* out = (float*)d_out;

    // ---- carve workspace (256B-aligned chunks), ~67 MB ----
    char* p = (char*)d_ws;
    unsigned short* h = (unsigned short*)p;  p += (size_t)Nn * 128 * 2;      // 25.6 MB
    unsigned short* ef = (unsigned short*)p; p += (size_t)Ne * 128 * 2;      // 25.6 MB
    int* gcurN = (int*)p;                    p += NBK * 4 + 192;             // bucket fills
    int* gcurE = (int*)p;                    p += NBK * 4 + 192;
    unsigned int* pairsN = (unsigned int*)p; p += (size_t)NBK * CAPB * 4;    // 8.0 MB padded
    unsigned int* pairsE = (unsigned int*)p; p += (size_t)NBK * CAPB * 4;    // 8.0 MB padded

    // zero the bucket-fill cursors (contiguous pair of arrays)
    hipMemsetAsync(gcurN, 0, 2 * (NBK * 4 + 192), stream);

    // ---- 3-launch pipeline: scatter+gemm256 -> bucketgatherE -> bucketgatherN ----
    scatter_gemm_kernel<<<NBLK + GEMM_TOTAL, 256, 0, stream>>>(nidx, eidx, gcurN, gcurE,
                                                               pairsN, pairsE, x, w, h);
    bucketgather_kernel<0><<<NHB, 256, 0, stream>>>(pairsE, gcurE, h, nullptr, ef);
    bucketgather_kernel<1><<<NHB, 256, 0, stream>>>(pairsN, gcurN, ef, bias, out);
}

// Round 13
// 308.642 us; speedup vs baseline: 1.1241x; 1.1241x over previous
//
#include <hip/hip_runtime.h>

#define Nn 100000
#define Ne 100000
#define NNZC 1600000
#define NBLK 256          // blocks for scatter
#define CHUNK 6250        // NNZC / NBLK
#define BSH 8             // bucket = idx >> 8 (256 ids per bucket)
#define NBK 391           // ceil(100000/256)
#define CAPB 5120         // padded bucket capacity (mean 4096 + 16 sigma)
#define GEMM_TOTAL 391    // 256-row gemm tiles
#define LCAP 2816         // per-half-bucket LDS perm capacity (mean 2048 + 17 sigma)
#define NHB 782           // 2 half-buckets per bucket

typedef __attribute__((ext_vector_type(8))) short short8;
typedef __attribute__((ext_vector_type(4))) float floatx4;

__device__ inline unsigned short f2bf(float f) {
    union { float f; unsigned int i; } c; c.f = f;
    unsigned int i = c.i;
    return (unsigned short)((i + 0x7fffu + ((i >> 16) & 1u)) >> 16);  // RNE
}
__device__ inline unsigned int f2bf2(float lo, float hi) {  // packed RNE
    union { float f; unsigned int i; } a, b;
    a.f = lo; b.f = hi;
    const unsigned int x = (a.i + 0x7fffu + ((a.i >> 16) & 1u)) >> 16;
    const unsigned int y = (b.i + 0x7fffu + ((b.i >> 16) & 1u)) & 0xffff0000u;
    return x | y;
}

// LDS for the scatter+gemm kernel
union FusedLds {
    unsigned short wlds[128 * 136];            // 34816 B (gemm W staging)
    struct { int a[NBK]; int b[NBK]; } s;      // 3128 B (scatter counts/cursors)
};

// ---- gemm block body: h[256 rows] = bf16(x @ W); W staged ONCE, 4 row-groups ----
__device__ inline void gemm_block256(int gb, const float* __restrict__ x,
                                     const float* __restrict__ w,
                                     unsigned short* __restrict__ h,
                                     unsigned short* wlds, int tid) {
    const int wave = tid >> 6, lane = tid & 63;
    const int q = lane >> 4, r16 = lane & 15;

    // stage W: w[k*128+n] fp32 -> wlds[n*136+k] bf16
    for (int i = tid; i < 4096; i += 256) {
        const int k = i >> 5;
        const int n0 = (i & 31) << 2;
        const float4 wv = *(const float4*)(w + k * 128 + n0);
        wlds[(n0 + 0) * 136 + k] = f2bf(wv.x);
        wlds[(n0 + 1) * 136 + k] = f2bf(wv.y);
        wlds[(n0 + 2) * 136 + k] = f2bf(wv.z);
        wlds[(n0 + 3) * 136 + k] = f2bf(wv.w);
    }
    __syncthreads();

#pragma unroll 1
    for (int rg = 0; rg < 4; ++rg) {
        const int row0 = gb * 256 + rg * 64 + wave * 16;
        const int rrow = min(row0 + r16, Nn - 1);

        floatx4 acc[8];
#pragma unroll
        for (int jb = 0; jb < 8; ++jb) acc[jb] = (floatx4){0.f, 0.f, 0.f, 0.f};

        const float* ap = x + (size_t)rrow * 128 + q * 8;
#pragma unroll
        for (int kk = 0; kk < 4; ++kk) {
            const float4 a0 = *(const float4*)(ap + kk * 32);
            const float4 a1 = *(const float4*)(ap + kk * 32 + 4);
            union { unsigned int u[4]; short8 s; } xf;
            xf.u[0] = f2bf2(a0.x, a0.y);
            xf.u[1] = f2bf2(a0.z, a0.w);
            xf.u[2] = f2bf2(a1.x, a1.y);
            xf.u[3] = f2bf2(a1.z, a1.w);
            const unsigned short* wp = wlds + kk * 32 + q * 8;
#pragma unroll
            for (int jb = 0; jb < 8; ++jb) {
                const short8 wf = *(const short8*)(wp + (jb * 16 + r16) * 136);
                acc[jb] = __builtin_amdgcn_mfma_f32_16x16x32_bf16(wf, xf.s, acc[jb], 0, 0, 0);
            }
        }

        if (row0 + r16 < Nn) {
            unsigned short* hb = h + (size_t)(row0 + r16) * 128 + q * 4;
#pragma unroll
            for (int jb = 0; jb < 8; ++jb) {
                uint2 o;
                o.x = f2bf2(acc[jb][0], acc[jb][1]);
                o.y = f2bf2(acc[jb][2], acc[jb][3]);
                *(uint2*)(hb + jb * 16) = o;
            }
        }
    }
}

// ---- fused: padded-bucket scatter (blocks [0,NBLK)) + gemm256 (rest) ----
__global__ __launch_bounds__(256) void scatter_gemm_kernel(
        const int* __restrict__ nidx, const int* __restrict__ eidx,
        int* __restrict__ gcurN, int* __restrict__ gcurE,
        unsigned int* __restrict__ pairsN, unsigned int* __restrict__ pairsE,
        const float* __restrict__ x, const float* __restrict__ w,
        unsigned short* __restrict__ h) {
    __shared__ FusedLds sm;
    const int tid = threadIdx.x;
    if (blockIdx.x < NBLK) {
        // pass 1: count
        for (int j = tid; j < NBK; j += 256) { sm.s.a[j] = 0; sm.s.b[j] = 0; }
        __syncthreads();
        const int base = blockIdx.x * CHUNK;
        for (int i = base + tid; i < base + CHUNK; i += 256) {
            atomicAdd(&sm.s.a[nidx[i] >> BSH], 1);
            atomicAdd(&sm.s.b[eidx[i] >> BSH], 1);
        }
        __syncthreads();
        // reserve contiguous ranges via memory-side returning atomics
        for (int j = tid; j < NBK; j += 256) {
            sm.s.a[j] = atomicAdd(&gcurN[j], sm.s.a[j]);
            sm.s.b[j] = atomicAdd(&gcurE[j], sm.s.b[j]);
        }
        __syncthreads();
        // pass 2: place (idx re-read is L2-hot)
        for (int i = base + tid; i < base + CHUNK; i += 256) {
            const int n = nidx[i], e = eidx[i];
            const int pn = atomicAdd(&sm.s.a[n >> BSH], 1);
            if (pn < CAPB)
                pairsN[(size_t)(n >> BSH) * CAPB + pn] =
                    ((unsigned int)e << 8) | (unsigned int)(n & 255);
            const int pe = atomicAdd(&sm.s.b[e >> BSH], 1);
            if (pe < CAPB)
                pairsE[(size_t)(e >> BSH) * CAPB + pe] =
                    ((unsigned int)n << 8) | (unsigned int)(e & 255);
        }
    } else {
        gemm_block256(blockIdx.x - NBLK, x, w, h, sm.wlds, tid);
    }
}

// ---- bucket-gather (512 threads = 8 waves): block owns 128 ids (half bucket).
// Sort the half-bucket into LDS CSR, then the proven 8-deep streaming gather;
// each wave owns 16 ids. 782 blocks x 8 waves = 24 waves/CU (R12 had 12 -> MLP-
// starved at 2 TB/s; this restores the ~21-24 waves/CU of the proven gather).
template <int MODE>
__global__ __launch_bounds__(512) void bucketgather_kernel(
        const unsigned int* __restrict__ pairs, const int* __restrict__ gcur,
        const void* __restrict__ srcv, const float* __restrict__ bias,
        void* __restrict__ outv) {
    __shared__ int perm_lds[LCAP];      // 11264 B
    __shared__ int offs_lds[129];
    __shared__ int cnt[128];
    __shared__ int cur[128];
    __shared__ int tmp[2][128];
    const int b = blockIdx.x >> 1;
    const int half = blockIdx.x & 1;
    const int tid = threadIdx.x;
    const int wave = tid >> 6, lane = tid & 63;

    const int fill = min(gcur[b], CAPB);
    const unsigned int* pb = pairs + (size_t)b * CAPB;

    // count this half's local ids (bit 7 selects half; low 7 bits = local id)
    if (tid < 128) cnt[tid] = 0;
    __syncthreads();
    for (int i = tid; i < fill; i += 512) {
        const unsigned int p = pb[i];
        if ((int)((p >> 7) & 1u) == half) atomicAdd(&cnt[p & 127u], 1);
    }
    __syncthreads();
    // exclusive scan of 128 counts (Hillis-Steele on tid<128)
    int v = 0, pin = 0;
    if (tid < 128) { v = cnt[tid]; tmp[0][tid] = v; }
    for (int off = 1; off < 128; off <<= 1) {
        __syncthreads();
        if (tid < 128) {
            int val = tmp[pin][tid];
            if (tid >= off) val += tmp[pin][tid - off];
            tmp[1 - pin][tid] = val;
        }
        pin ^= 1;
    }
    __syncthreads();
    if (tid < 128) {
        const int excl = tmp[pin][tid] - v;
        offs_lds[tid] = excl;
        cur[tid] = excl;
        if (tid == 127) offs_lds[128] = tmp[pin][127];
    }
    __syncthreads();
    // place (bucket re-read is L2-hot; sibling half-block shares the lines)
    for (int i = tid; i < fill; i += 512) {
        const unsigned int p = pb[i];
        if ((int)((p >> 7) & 1u) == half) {
            const int pos = atomicAdd(&cur[p & 127u], 1);
            if (pos < LCAP) perm_lds[pos] = (int)(p >> 8);
        }
    }
    __syncthreads();

    // ---- proven flattened streaming gather, LDS-fed (wave owns 16 ids) ----
    const int i0 = wave << 4;
    const int start = offs_lds[i0];
    const int end = offs_lds[i0 + 16];
    const int pmax = min(offs_lds[128], LCAP) - 1;
    const unsigned int l4 = (unsigned int)lane << 2;
    const char* src = (const char*)srcv;

    float bx = 0.f, by = 0.f;
    if (MODE == 1) {
        const float2 bb = ((const float2*)bias)[lane];
        bx = bb.x; by = bb.y;
    }

    float ax = 0.f, ay = 0.f;
    int e = i0;
    int seg_start = start;
    int nb = offs_lds[i0 + 1];
    const int gidbase = (b << 8) + (half << 7);

    auto flush = [&](int deg) {
        const int gid = gidbase + e;
        if (gid < 100000) {
            const float sinv = deg ? 1.f / (float)deg : 0.f;
            if (MODE == 0) {
                *(unsigned int*)((char*)outv + (((size_t)gid) << 8) + l4) =
                    f2bf2(ax * sinv, ay * sinv);
            } else {
                float2 o;
                o.x = ax * sinv + bx;
                o.y = ay * sinv + by;
                *(float2*)((char*)outv + (((size_t)gid) << 9) + ((size_t)l4 << 1)) = o;
            }
        }
        ax = 0.f; ay = 0.f;
        ++e;
    };

    int myv = 0;
    for (int i = start; i < end; i += 8) {
        const int t = (i - start) & 63;
        if (t == 0) myv = perm_lds[min(i + lane, pmax)];   // ds_read window
        const int m = min(end - i, 8);
        unsigned int a[8], u[8];
#pragma unroll
        for (int j = 0; j < 8; ++j)
            a[j] = ((unsigned int)__shfl(myv, t + (j < m ? j : m - 1), 64) << 8) | l4;
#pragma unroll
        for (int j = 0; j < 8; ++j) u[j] = *(const unsigned int*)(src + a[j]);
#pragma unroll
        for (int j = 0; j < 8; ++j) {
            if (j < m) {  // wave-uniform
                while (i + j == nb) {  // segment boundary (handles empty segments)
                    flush(nb - seg_start);
                    seg_start = nb;
                    nb = offs_lds[e + 1];
                }
                ax += __uint_as_float(u[j] << 16);
                ay += __uint_as_float(u[j] & 0xffff0000u);
            }
        }
    }
    while (e < i0 + 16) {    // trailing (possibly empty) segments
        flush(end - seg_start);
        seg_start = end;
    }
}

extern "C" void kernel_launch(void* const* d_in, const int* in_sizes, int n_in,
                              void* d_out, int out_size, void* d_ws, size_t ws_size,
                              hipStream_t stream) {
    const float* x = (const float*)d_in[0];
    const float* w = (const float*)d_in[1];
    const float* bias = (const float*)d_in[2];
    const int* hei = (const int*)d_in[3];
    const int* nidx = hei;            // row 0: node indices
    const int* eidx = hei + NNZC;     // row 1: edge indices
    float* out = (float*)d_out;

    // ---- carve workspace (256B-aligned chunks), ~67 MB ----
    char* p = (char*)d_ws;
    unsigned short* h = (unsigned short*)p;  p += (size_t)Nn * 128 * 2;      // 25.6 MB
    unsigned short* ef = (unsigned short*)p; p += (size_t)Ne * 128 * 2;      // 25.6 MB
    int* gcurN = (int*)p;                    p += NBK * 4 + 192;             // bucket fills
    int* gcurE = (int*)p;                    p += NBK * 4 + 192;
    unsigned int* pairsN = (unsigned int*)p; p += (size_t)NBK * CAPB * 4;    // 8.0 MB padded
    unsigned int* pairsE = (unsigned int*)p; p += (size_t)NBK * CAPB * 4;    // 8.0 MB padded

    // zero the bucket-fill cursors (contiguous pair of arrays)
    hipMemsetAsync(gcurN, 0, 2 * (NBK * 4 + 192), stream);

    // ---- 3-launch pipeline: scatter+gemm256 -> bucketgatherE -> bucketgatherN ----
    scatter_gemm_kernel<<<NBLK + GEMM_TOTAL, 256, 0, stream>>>(nidx, eidx, gcurN, gcurE,
                                                               pairsN, pairsE, x, w, h);
    bucketgather_kernel<0><<<NHB, 512, 0, stream>>>(pairsE, gcurE, h, nullptr, ef);
    bucketgather_kernel<1><<<NHB, 512, 0, stream>>>(pairsN, gcurN, ef, bias, out);
}